// Round 17
// baseline (191.193 us; speedup 1.0000x reference)
//
#include <hip/hip_runtime.h>
#include <hip/hip_bf16.h>

// dims: Bk=16, n=256, E=768, G=128, Cout_g=256, Cin_g=192, B=4, K=4, L=16, H=16, D=64
// out = [pooled 16*768][batch 131072*Tmax][valid 4*Tmax]
// ws layout: int ctrl[64] @0 ([0..15] len, [16..31] cum, [32..35] total);
//            Wp u16 @byte 1024: [ls][kk] 64KB panels, LDS-linear w/ XOR swizzle baked
//            Lp u16 @byte 1024+12582912: lh bf16 flat
// decode: g = ls*4 + beta, d = beta*16 + (o>>4), h = o&15

typedef float f32x4 __attribute__((ext_vector_type(4)));
typedef __bf16 bf16x8 __attribute__((ext_vector_type(8)));
typedef unsigned short u16x4 __attribute__((ext_vector_type(4)));
typedef unsigned short u16x8 __attribute__((ext_vector_type(8)));

__device__ __forceinline__ unsigned short f2bf(float f) {
    union { float f; unsigned u; } v; v.f = f;
    unsigned r = v.u + 0x7FFFu + ((v.u >> 16) & 1u);
    return (unsigned short)(r >> 16);
}

__device__ __forceinline__ bf16x8 ldfrag(const unsigned short* p) {
    u16x8 r = *(const u16x8*)p;
    return __builtin_bit_cast(bf16x8, r);
}

// unconditional load + per-lane zero select (keeps vmcnt issue count exec-independent)
__device__ __forceinline__ bf16x8 ldfrag_masked(const unsigned short* p, bool valid) {
    u16x8 r = *(const u16x8*)p;
    u16x8 z = {};
    r = valid ? r : z;
    return __builtin_bit_cast(bf16x8, r);
}

// ---- merged prep: [0,3072) wgt pack | [3072,4608) lh pack | [4608,4800) pooled | 4800 cums ----
__global__ void prep_kernel(const float* __restrict__ wgt, const float* __restrict__ lh,
                            const int* __restrict__ mask,
                            unsigned short* __restrict__ Wp, unsigned short* __restrict__ Lp,
                            int* __restrict__ ws, float* __restrict__ pooled,
                            float* __restrict__ valid_out, int Tmax) {
    __shared__ float red[4][64];
    __shared__ float mred[4];
    int bid = blockIdx.x;
    int tid = threadIdx.x;

    if (bid < 3072) {
        int ls = bid / 96;
        int rem = bid - ls * 96;
        int kk = rem >> 4;
        int blk = rem & 15;
        int slot = (blk << 8) + tid;
        int row = slot >> 2;
        int sc = slot & 3;
        int coloff = (sc ^ ((row >> 1) & 3)) << 3;
        const float* src = wgt + (size_t)ls * 196608 + row * 192 + (kk << 5) + coloff;
        f32x4 a0 = *(const f32x4*)src;
        f32x4 a1 = *(const f32x4*)(src + 4);
        u16x8 w = { f2bf(a0[0]), f2bf(a0[1]), f2bf(a0[2]), f2bf(a0[3]),
                    f2bf(a1[0]), f2bf(a1[1]), f2bf(a1[2]), f2bf(a1[3]) };
        *(u16x8*)(Wp + (((size_t)(ls * 6 + kk) << 12) + slot) * 8) = w;
    } else if (bid < 4608) {
        size_t slot = (size_t)(bid - 3072) * 256 + tid;   // < 393216
        const float* src = lh + slot * 8;
        f32x4 a0 = *(const f32x4*)src;
        f32x4 a1 = *(const f32x4*)(src + 4);
        u16x8 w = { f2bf(a0[0]), f2bf(a0[1]), f2bf(a0[2]), f2bf(a0[3]),
                    f2bf(a1[0]), f2bf(a1[1]), f2bf(a1[2]), f2bf(a1[3]) };
        *(u16x8*)(Lp + slot * 8) = w;
    } else if (bid < 4800) {
        // pooled, self-contained (computes its own mask-sum)
        int r = bid - 4608;            // 0..191
        int bs = r / 12, ec = r - bs * 12;
        int tg = tid >> 6, lane = tid & 63;
        int e = ec * 64 + lane;
        float s = 0.f, mc = 0.f;
        for (int t = tg; t < 256; t += 4) {
            float mf = (float)mask[bs * 256 + t];
            s += lh[(size_t)(bs * 256 + t) * 768 + e] * mf;
            mc += mf;
        }
        red[tg][lane] = s;
        if (lane == 0) mred[tg] = mc;
        __syncthreads();
        if (tg == 0) {
            float tot = red[0][lane] + red[1][lane] + red[2][lane] + red[3][lane];
            float len = mred[0] + mred[1] + mred[2] + mred[3];
            pooled[bs * 768 + e] = tot / len;
        }
    } else {
        // cums: lens, prefix sums, valid flags
        int w = tid >> 6, lane = tid & 63;
        for (int bs = w; bs < 16; bs += 4) {
            int m = mask[bs * 256 + lane] + mask[bs * 256 + lane + 64] +
                    mask[bs * 256 + lane + 128] + mask[bs * 256 + lane + 192];
#pragma unroll
            for (int off = 32; off > 0; off >>= 1) m += __shfl_down(m, off);
            if (lane == 0) ws[bs] = m;
        }
        __syncthreads();
        if (tid == 0) {
            for (int b = 0; b < 4; ++b) {
                int c = 0;
                for (int j = 0; j < 4; ++j) { ws[16 + b * 4 + j] = c; c += ws[b * 4 + j]; }
                ws[32 + b] = c;
            }
        }
        __syncthreads();
        for (int i = tid; i < 4 * Tmax; i += 256) {
            int b = i / Tmax;
            int T = i - b * Tmax;
            valid_out[i] = (T < ws[32 + b]) ? 1.0f : 0.0f;
        }
    }
}

// T-space all-beta GEMM, barrier-free K-loop, wave-private staging with
// HALF-CHUNK PING-PONG: wave's 8KB region split into two 4KB halves; while one
// half's MFMA runs, the other half's global_load_lds is in flight. Deterministic
// per-wave vmcnt counts: queue = [h0(cc)x4, B(cc)x2, h1(cc)x4] -> vmcnt(4)/vmcnt(6).
__global__ __launch_bounds__(512, 4) void gemm_t(
    const unsigned short* __restrict__ Wp, const unsigned short* __restrict__ Lp,
    const float* __restrict__ bias, const int* __restrict__ ws,
    float* __restrict__ out, int Tmax, int nT) {
    __shared__ __align__(16) unsigned short As[1024][32];   // 64KB; reused as Ltr f32[128][68]
    __shared__ __align__(16) float biasT[16][64];           // 4KB

    int x = blockIdx.x;
    int xcd = x & 7;
    int rest = x >> 3;
    int per = nT << 2;
    int lsq = rest / per;
    int j = rest - lsq * per;
    int ls = (lsq << 3) + xcd;      // pinned per XCD
    int b = j / nT;
    int Tt = j - b * nT;
    int Tbase = Tt << 5;

    int total = ws[32 + b];
    int tid = threadIdx.x;
    int lane = tid & 63;
    int wv = tid >> 6;
    int toff = lane & 3, dcq = lane >> 2;
    float* batch = out + 12288;
    size_t hd0 = (size_t)((ls << 2) + b) << 4;

    // fully-tail block: pure zero-store, no GEMM
    if (Tbase >= total) {
        f32x4 z = {0.f, 0.f, 0.f, 0.f};
#pragma unroll
        for (int r = 0; r < 4; ++r) {
#pragma unroll
            for (int gi = 0; gi < 4; ++gi) {
                int flat = (wv << 2) + gi;
                int hq = flat >> 3, t4 = flat & 7;
                int tglob = Tbase + (t4 << 2) + toff;
                int h = (hq << 2) + r;
                if (tglob < Tmax) {
                    float* dst = batch + ((hd0 + h) * (size_t)Tmax + tglob) * 64;
                    *(f32x4*)(dst + (dcq << 2)) = z;
                }
            }
        }
        return;
    }

    int beta = wv >> 1, oh = wv & 1;
    int p = lane & 15, q = lane >> 4;

    // per-lane B row decode (clamped -> addresses always valid)
    int c1 = ws[16 + (b << 2) + 1];
    int c2 = ws[16 + (b << 2) + 2];
    int c3 = ws[16 + (b << 2) + 3];
    const unsigned short* Brow[2];
    bool bval[2];
#pragma unroll
    for (int n = 0; n < 2; ++n) {
        int Ti = Tbase + (n << 4) + p;
        bval[n] = Ti < total;
        int TiC = bval[n] ? Ti : (total - 1);
        int sj = (TiC >= c1) + (TiC >= c2) + (TiC >= c3);
        int cum = sj == 0 ? 0 : (sj == 1 ? c1 : (sj == 2 ? c2 : c3));
        int row = ((b << 2) + sj) * 256 + (TiC - cum);
        Brow[n] = Lp + (size_t)row * 768 + beta * 192 + (q << 3);
    }

    const char* gpanel = (const char*)Wp + (((size_t)(ls * 6)) << 16) + (wv << 13) + (lane << 4);
    char* lbase = ((char*)&As[0][0]) + (wv << 13);

    f32x4 acc[8][2] = {};
    const bf16x8 bz = {};

    // prologue: h0(0) x4, B(0) x2, h1(0) x4  -> 10 outstanding
#pragma unroll
    for (int it = 0; it < 4; ++it)
        __builtin_amdgcn_global_load_lds(
            (const __attribute__((address_space(1))) void*)(gpanel + it * 1024),
            (__attribute__((address_space(3))) void*)(lbase + it * 1024), 16, 0, 0);
    bf16x8 bc0 = ldfrag_masked(Brow[0], bval[0]);
    bf16x8 bc1 = ldfrag_masked(Brow[1], bval[1]);
#pragma unroll
    for (int it = 4; it < 8; ++it)
        __builtin_amdgcn_global_load_lds(
            (const __attribute__((address_space(1))) void*)(gpanel + it * 1024),
            (__attribute__((address_space(3))) void*)(lbase + it * 1024), 16, 0, 0);

    bf16x8 bn0, bn1;

#pragma unroll
    for (int cc = 0; cc < 6; ++cc) {
        // h0(cc) + B(cc) done (oldest 6 of 10 retired); h1(cc) still in flight
        asm volatile("s_waitcnt vmcnt(4)" ::: "memory");
        __builtin_amdgcn_sched_barrier(0);
#pragma unroll
        for (int r8 = 0; r8 < 4; ++r8) {
            int row = (wv << 7) + (r8 << 4) + p;
            bf16x8 af = ldfrag(&As[row][(q ^ ((row >> 1) & 3)) << 3]);
            acc[r8][0] = __builtin_amdgcn_mfma_f32_16x16x32_bf16(af, bc0, acc[r8][0], 0, 0, 0);
            acc[r8][1] = __builtin_amdgcn_mfma_f32_16x16x32_bf16(af, bc1, acc[r8][1], 0, 0, 0);
        }
        asm volatile("s_waitcnt lgkmcnt(0)" ::: "memory");   // h0 frag reads done
        __builtin_amdgcn_sched_barrier(0);
        if (cc < 5) {
            const char* g = gpanel + ((size_t)(cc + 1) << 16);
#pragma unroll
            for (int it = 0; it < 4; ++it)
                __builtin_amdgcn_global_load_lds(
                    (const __attribute__((address_space(1))) void*)(g + it * 1024),
                    (__attribute__((address_space(3))) void*)(lbase + it * 1024), 16, 0, 0);
            bn0 = ldfrag_masked(Brow[0] + ((cc + 1) << 5), bval[0]);
            bn1 = ldfrag_masked(Brow[1] + ((cc + 1) << 5), bval[1]);
            // outstanding: h1(cc)x4 (oldest) + h0(cc+1)x4 + B(cc+1)x2 = 10
            asm volatile("s_waitcnt vmcnt(6)" ::: "memory"); // retire h1(cc)
        } else {
            bn0 = bz; bn1 = bz;
            asm volatile("s_waitcnt vmcnt(0)" ::: "memory");
        }
        __builtin_amdgcn_sched_barrier(0);
#pragma unroll
        for (int r8 = 4; r8 < 8; ++r8) {
            int row = (wv << 7) + (r8 << 4) + p;
            bf16x8 af = ldfrag(&As[row][(q ^ ((row >> 1) & 3)) << 3]);
            acc[r8][0] = __builtin_amdgcn_mfma_f32_16x16x32_bf16(af, bc0, acc[r8][0], 0, 0, 0);
            acc[r8][1] = __builtin_amdgcn_mfma_f32_16x16x32_bf16(af, bc1, acc[r8][1], 0, 0, 0);
        }
        asm volatile("s_waitcnt lgkmcnt(0)" ::: "memory");   // h1 frag reads done
        __builtin_amdgcn_sched_barrier(0);
        if (cc < 5) {
            const char* g = gpanel + ((size_t)(cc + 1) << 16);
#pragma unroll
            for (int it = 4; it < 8; ++it)
                __builtin_amdgcn_global_load_lds(
                    (const __attribute__((address_space(1))) void*)(g + it * 1024),
                    (__attribute__((address_space(3))) void*)(lbase + it * 1024), 16, 0, 0);
        }
        bc0 = bn0; bc1 = bn1;
    }

    // bias -> biasT[h][beta*16+dmid] (loads AFTER the counted-vmcnt region;
    // visibility to other waves guaranteed by the first epilogue __syncthreads)
    {
        int i0 = tid, i1 = tid + 512;
        biasT[i0 & 15][((i0 >> 8) << 4) + ((i0 & 255) >> 4)] = bias[(ls << 10) + i0];
        biasT[i1 & 15][((i1 >> 8) << 4) + ((i1 & 255) >> 4)] = bias[(ls << 10) + i1];
    }

    __syncthreads();   // all waves done with As before Ltr reuse

    // ---- epilogue: transpose via Ltr f32[128][68], 1KB-burst stores, tail zeros ----
    float* Ltr = (float*)&As[0][0];
    int col0 = (beta << 4) + (oh << 3);

#pragma unroll
    for (int r = 0; r < 4; ++r) {
#pragma unroll
        for (int n = 0; n < 2; ++n) {
            int rowL = (((n << 4) + p) << 2) + q;
            f32x4 v0 = { acc[0][n][r], acc[1][n][r], acc[2][n][r], acc[3][n][r] };
            f32x4 v1 = { acc[4][n][r], acc[5][n][r], acc[6][n][r], acc[7][n][r] };
            *(f32x4*)(Ltr + rowL * 68 + col0) = v0;
            *(f32x4*)(Ltr + rowL * 68 + col0 + 4) = v1;
        }
        __syncthreads();
#pragma unroll
        for (int gi = 0; gi < 4; ++gi) {
            int flat = (wv << 2) + gi;
            int hq = flat >> 3, t4 = flat & 7;
            int tloc = (t4 << 2) + toff;
            int h = (hq << 2) + r;
            int tglob = Tbase + tloc;
            if (tglob < Tmax) {
                f32x4 v;
                if (tglob < total) {
                    v = *(const f32x4*)(Ltr + ((tloc << 2) + hq) * 68 + (dcq << 2));
                    v += *(const f32x4*)&biasT[h][dcq << 2];
                } else {
                    v = (f32x4){0.f, 0.f, 0.f, 0.f};
                }
                float* dst = batch + ((hd0 + h) * (size_t)Tmax + tglob) * 64;
                *(f32x4*)(dst + (dcq << 2)) = v;
            }
        }
        __syncthreads();
    }
}

// ---------------- fallback path (ws too small) ----------------
__global__ void cums_kernel(const int* __restrict__ mask, int* __restrict__ ws,
                            float* __restrict__ valid_out, int Tmax) {
    int tid = threadIdx.x;
    int w = tid >> 6, lane = tid & 63;
    int m = mask[w * 256 + lane] + mask[w * 256 + lane + 64] +
            mask[w * 256 + lane + 128] + mask[w * 256 + lane + 192];
#pragma unroll
    for (int off = 32; off > 0; off >>= 1) m += __shfl_down(m, off);
    if (lane == 0) ws[w] = m;
    __syncthreads();
    if (tid == 0) {
        for (int b = 0; b < 4; ++b) {
            int c = 0;
            for (int j = 0; j < 4; ++j) { ws[16 + b * 4 + j] = c; c += ws[b * 4 + j]; }
            ws[32 + b] = c;
        }
    }
    __syncthreads();
    for (int i = tid; i < 4 * Tmax; i += 1024) {
        int b = i / Tmax;
        int T = i - b * Tmax;
        valid_out[i] = (T < ws[32 + b]) ? 1.0f : 0.0f;
    }
}

__global__ void pooled_kernel(const float* __restrict__ lh, const int* __restrict__ mask,
                              const int* __restrict__ ws, float* __restrict__ pooled) {
    int bs = blockIdx.x / 12;
    int ec = blockIdx.x - bs * 12;
    int tid = threadIdx.x;
    int tg = tid >> 6, lane = tid & 63;
    int e = ec * 64 + lane;
    float s = 0.f;
    for (int t = tg; t < 256; t += 4) {
        float mf = (float)mask[bs * 256 + t];
        s += lh[(size_t)(bs * 256 + t) * 768 + e] * mf;
    }
    __shared__ float red[4][64];
    red[tg][lane] = s;
    __syncthreads();
    if (tg == 0) {
        float tot = red[0][lane] + red[1][lane] + red[2][lane] + red[3][lane];
        pooled[bs * 768 + e] = tot / (float)ws[bs];
    }
}

__global__ void zerotail_kernel(float* __restrict__ batch, const int* __restrict__ ws,
                                int Tmax) {
    int rr = blockIdx.x;
    int b = rr >> 9;
    int rem = rr & 511;
    int l = rem >> 5, s = (rem >> 4) & 1, h = rem & 15;
    int total = ws[32 + b];
    int span = Tmax - total;
    if (span <= 0) return;
    float* row = batch + (((size_t)((l * 2 + s) * 4 + b) * 16 + h) * (size_t)Tmax + total) * 64;
    f32x4 z = {0.f, 0.f, 0.f, 0.f};
    int nchunk = span << 4;
    for (int j = threadIdx.x; j < nchunk; j += 256)
        *(f32x4*)(row + (j << 2)) = z;
}

__global__ __launch_bounds__(512, 4) void gemm_fb(
    const float* __restrict__ lh, const float* __restrict__ wgt,
    const float* __restrict__ bias, const int* __restrict__ ws,
    float* __restrict__ out, int Tmax) {
    __shared__ __align__(16) unsigned short As[1024][32];
    __shared__ __align__(16) float biasT[16][64];

    int x = blockIdx.x;
    int xcd = x & 7;
    int rest = x >> 3;
    int lsq = rest >> 7;
    int rb = rest & 127;
    int ls = (lsq << 3) + xcd;
    int bs = rb >> 3;
    int tq = rb & 7;

    int len = ws[bs];
    int tbase = tq << 5;
    if (tbase >= len) return;

    int tid = threadIdx.x;
    {
        int i0 = tid, i1 = tid + 512;
        biasT[i0 & 15][((i0 >> 8) << 4) + ((i0 & 255) >> 4)] = bias[(ls << 10) + i0];
        biasT[i1 & 15][((i1 >> 8) << 4) + ((i1 & 255) >> 4)] = bias[(ls << 10) + i1];
    }

    int lane = tid & 63;
    int wv = tid >> 6;
    int beta = wv >> 1, oh = wv & 1;
    int p = lane & 15, q = lane >> 4;

    f32x4 acc[8][2] = {};

#pragma unroll
    for (int cc = 0; cc < 6; ++cc) {
        const int kk = cc << 5;
        const float* Awg = wgt + (size_t)ls * 196608;
        int arow0 = tid >> 2;
        int achk = tid & 3;
#pragma unroll
        for (int it = 0; it < 8; ++it) {
            int row = arow0 + (it << 7);
            const float* src = Awg + row * 192 + kk + (achk << 3);
            f32x4 a0 = *(const f32x4*)src;
            f32x4 a1 = *(const f32x4*)(src + 4);
            u16x8 aw = { f2bf(a0[0]), f2bf(a0[1]), f2bf(a0[2]), f2bf(a0[3]),
                         f2bf(a1[0]), f2bf(a1[1]), f2bf(a1[2]), f2bf(a1[3]) };
            *(u16x8*)&As[row][(achk ^ ((row >> 1) & 3)) << 3] = aw;
        }
        bf16x8 bf[2];
        const float* Brow = lh + (size_t)bs * 196608 + (size_t)(tbase + p) * 768 +
                            beta * 192 + (q << 3) + kk;
#pragma unroll
        for (int n = 0; n < 2; ++n) {
            const float* bp = Brow + n * 16 * 768;
            f32x4 b0 = *(const f32x4*)bp;
            f32x4 b1 = *(const f32x4*)(bp + 4);
            u16x8 bw = { f2bf(b0[0]), f2bf(b0[1]), f2bf(b0[2]), f2bf(b0[3]),
                         f2bf(b1[0]), f2bf(b1[1]), f2bf(b1[2]), f2bf(b1[3]) };
            bf[n] = __builtin_bit_cast(bf16x8, bw);
        }
        __syncthreads();
#pragma unroll
        for (int r8 = 0; r8 < 8; ++r8) {
            int row = (beta << 8) + (oh << 7) + (r8 << 4) + p;
            bf16x8 af = ldfrag(&As[row][(q ^ ((row >> 1) & 3)) << 3]);
            acc[r8][0] = __builtin_amdgcn_mfma_f32_16x16x32_bf16(af, bf[0], acc[r8][0], 0, 0, 0);
            acc[r8][1] = __builtin_amdgcn_mfma_f32_16x16x32_bf16(af, bf[1], acc[r8][1], 0, 0, 0);
        }
        __syncthreads();
    }

    float* Ltr = (float*)&As[0][0];
    int cum = ws[16 + bs];
    int b = bs >> 2;
    float* batch = out + 12288;
    size_t hd0 = (size_t)((ls << 2) + b) << 4;

    int toff = lane & 3, dcq = lane >> 2;
    int col0 = (beta << 4) + (oh << 3);

#pragma unroll
    for (int r = 0; r < 4; ++r) {
#pragma unroll
        for (int n = 0; n < 2; ++n) {
            int rowL = (((n << 4) + p) << 2) + q;
            f32x4 v0 = { acc[0][n][r], acc[1][n][r], acc[2][n][r], acc[3][n][r] };
            f32x4 v1 = { acc[4][n][r], acc[5][n][r], acc[6][n][r], acc[7][n][r] };
            *(f32x4*)(Ltr + rowL * 68 + col0) = v0;
            *(f32x4*)(Ltr + rowL * 68 + col0 + 4) = v1;
        }
        __syncthreads();
#pragma unroll
        for (int gi = 0; gi < 4; ++gi) {
            int flat = (wv << 2) + gi;
            int hq = flat >> 3, t4 = flat & 7;
            int tloc = (t4 << 2) + toff;
            int h = (hq << 2) + r;
            int tglob = tbase + tloc;
            f32x4 v = *(const f32x4*)(Ltr + ((tloc << 2) + hq) * 68 + (dcq << 2));
            v += *(const f32x4*)&biasT[h][dcq << 2];
            if (tglob < len) {
                float* dst = batch + ((hd0 + h) * (size_t)Tmax + cum + tglob) * 64;
                *(f32x4*)(dst + (dcq << 2)) = v;
            }
        }
        __syncthreads();
    }
}

extern "C" void kernel_launch(void* const* d_in, const int* in_sizes, int n_in,
                              void* d_out, int out_size, void* d_ws, size_t ws_size,
                              hipStream_t stream) {
    const float* lh   = (const float*)d_in[0];
    const int*   mask = (const int*)d_in[1];
    const float* wgt  = (const float*)d_in[2];
    const float* bias = (const float*)d_in[3];
    float* out = (float*)d_out;
    int* ws = (int*)d_ws;

    int Tmax = (out_size - 12288) / 131076;
    int nT = (Tmax + 31) >> 5;

    unsigned short* Wp = (unsigned short*)((char*)d_ws + 1024);
    unsigned short* Lp = (unsigned short*)((char*)d_ws + 1024 + 12582912);
    const size_t need = 1024 + 12582912 + 6291456;
    bool packed = ws_size >= need;

    float* valid_out = out + 12288 + (size_t)131072 * Tmax;

    if (packed) {
        prep_kernel<<<4801, 256, 0, stream>>>(wgt, lh, mask, Wp, Lp, ws, out, valid_out, Tmax);
        gemm_t<<<128 * nT, 512, 0, stream>>>(Wp, Lp, bias, ws, out, Tmax, nT);
    } else {
        cums_kernel<<<1, 1024, 0, stream>>>(mask, ws, valid_out, Tmax);
        pooled_kernel<<<16 * 12, 256, 0, stream>>>(lh, mask, ws, out);
        zerotail_kernel<<<2048, 256, 0, stream>>>(out + 12288, ws, Tmax);
        gemm_fb<<<4096, 512, 0, stream>>>(lh, wgt, bias, ws, out, Tmax);
    }
}

// Round 18
// 186.675 us; speedup vs baseline: 1.0242x; 1.0242x over previous
//
#include <hip/hip_runtime.h>
#include <hip/hip_bf16.h>

// dims: Bk=16, n=256, E=768, G=128, Cout_g=256, Cin_g=192, B=4, K=4, L=16, H=16, D=64
// out = [pooled 16*768][batch 131072*Tmax][valid 4*Tmax]
// ws layout: int ctrl[64] @0 ([0..15] len, [16..31] cum, [32..35] total);
//            Wp u16 @byte 1024: [ls][kk] 64KB panels, LDS-linear w/ XOR swizzle baked
//            Lp u16 @byte 1024+12582912: lh bf16 flat
// decode: g = ls*4 + beta, d = beta*16 + (o>>4), h = o&15

typedef float f32x4 __attribute__((ext_vector_type(4)));
typedef __bf16 bf16x8 __attribute__((ext_vector_type(8)));
typedef unsigned short u16x4 __attribute__((ext_vector_type(4)));
typedef unsigned short u16x8 __attribute__((ext_vector_type(8)));

__device__ __forceinline__ unsigned short f2bf(float f) {
    union { float f; unsigned u; } v; v.f = f;
    unsigned r = v.u + 0x7FFFu + ((v.u >> 16) & 1u);
    return (unsigned short)(r >> 16);
}

__device__ __forceinline__ bf16x8 ldfrag(const unsigned short* p) {
    u16x8 r = *(const u16x8*)p;
    return __builtin_bit_cast(bf16x8, r);
}

// unconditional load + per-lane zero select (keeps vmcnt issue count exec-independent)
__device__ __forceinline__ bf16x8 ldfrag_masked(const unsigned short* p, bool valid) {
    u16x8 r = *(const u16x8*)p;
    u16x8 z = {};
    r = valid ? r : z;
    return __builtin_bit_cast(bf16x8, r);
}

// ---- merged prep: [0,3072) wgt pack | [3072,4608) lh pack | [4608,4800) pooled | 4800 cums ----
__global__ void prep_kernel(const float* __restrict__ wgt, const float* __restrict__ lh,
                            const int* __restrict__ mask,
                            unsigned short* __restrict__ Wp, unsigned short* __restrict__ Lp,
                            int* __restrict__ ws, float* __restrict__ pooled,
                            float* __restrict__ valid_out, int Tmax) {
    __shared__ float red[4][64];
    __shared__ float mred[4];
    int bid = blockIdx.x;
    int tid = threadIdx.x;

    if (bid < 3072) {
        int ls = bid / 96;
        int rem = bid - ls * 96;
        int kk = rem >> 4;
        int blk = rem & 15;
        int slot = (blk << 8) + tid;
        int row = slot >> 2;
        int sc = slot & 3;
        int coloff = (sc ^ ((row >> 1) & 3)) << 3;
        const float* src = wgt + (size_t)ls * 196608 + row * 192 + (kk << 5) + coloff;
        f32x4 a0 = *(const f32x4*)src;
        f32x4 a1 = *(const f32x4*)(src + 4);
        u16x8 w = { f2bf(a0[0]), f2bf(a0[1]), f2bf(a0[2]), f2bf(a0[3]),
                    f2bf(a1[0]), f2bf(a1[1]), f2bf(a1[2]), f2bf(a1[3]) };
        *(u16x8*)(Wp + (((size_t)(ls * 6 + kk) << 12) + slot) * 8) = w;
    } else if (bid < 4608) {
        size_t slot = (size_t)(bid - 3072) * 256 + tid;   // < 393216
        const float* src = lh + slot * 8;
        f32x4 a0 = *(const f32x4*)src;
        f32x4 a1 = *(const f32x4*)(src + 4);
        u16x8 w = { f2bf(a0[0]), f2bf(a0[1]), f2bf(a0[2]), f2bf(a0[3]),
                    f2bf(a1[0]), f2bf(a1[1]), f2bf(a1[2]), f2bf(a1[3]) };
        *(u16x8*)(Lp + slot * 8) = w;
    } else if (bid < 4800) {
        // pooled, self-contained (computes its own mask-sum)
        int r = bid - 4608;            // 0..191
        int bs = r / 12, ec = r - bs * 12;
        int tg = tid >> 6, lane = tid & 63;
        int e = ec * 64 + lane;
        float s = 0.f, mc = 0.f;
        for (int t = tg; t < 256; t += 4) {
            float mf = (float)mask[bs * 256 + t];
            s += lh[(size_t)(bs * 256 + t) * 768 + e] * mf;
            mc += mf;
        }
        red[tg][lane] = s;
        if (lane == 0) mred[tg] = mc;
        __syncthreads();
        if (tg == 0) {
            float tot = red[0][lane] + red[1][lane] + red[2][lane] + red[3][lane];
            float len = mred[0] + mred[1] + mred[2] + mred[3];
            pooled[bs * 768 + e] = tot / len;
        }
    } else {
        // cums: lens, prefix sums, valid flags
        int w = tid >> 6, lane = tid & 63;
        for (int bs = w; bs < 16; bs += 4) {
            int m = mask[bs * 256 + lane] + mask[bs * 256 + lane + 64] +
                    mask[bs * 256 + lane + 128] + mask[bs * 256 + lane + 192];
#pragma unroll
            for (int off = 32; off > 0; off >>= 1) m += __shfl_down(m, off);
            if (lane == 0) ws[bs] = m;
        }
        __syncthreads();
        if (tid == 0) {
            for (int b = 0; b < 4; ++b) {
                int c = 0;
                for (int j = 0; j < 4; ++j) { ws[16 + b * 4 + j] = c; c += ws[b * 4 + j]; }
                ws[32 + b] = c;
            }
        }
        __syncthreads();
        for (int i = tid; i < 4 * Tmax; i += 256) {
            int b = i / Tmax;
            int T = i - b * Tmax;
            valid_out[i] = (T < ws[32 + b]) ? 1.0f : 0.0f;
        }
    }
}

// T-space all-beta GEMM, barrier-free K-loop, wave-private staging,
// B pipelined one chunk ahead with counted vmcnt(2).
__global__ __launch_bounds__(512, 4) void gemm_t(
    const unsigned short* __restrict__ Wp, const unsigned short* __restrict__ Lp,
    const float* __restrict__ bias, const int* __restrict__ ws,
    float* __restrict__ out, int Tmax, int nT) {
    __shared__ __align__(16) unsigned short As[1024][32];   // 64KB; reused as Ltr f32[128][68]
    __shared__ __align__(16) float biasT[16][64];           // 4KB

    int x = blockIdx.x;
    int xcd = x & 7;
    int rest = x >> 3;
    int per = nT << 2;
    int lsq = rest / per;
    int j = rest - lsq * per;
    int ls = (lsq << 3) + xcd;      // pinned per XCD
    int b = j / nT;
    int Tt = j - b * nT;
    int Tbase = Tt << 5;

    int total = ws[32 + b];
    int tid = threadIdx.x;
    int lane = tid & 63;
    int wv = tid >> 6;
    int toff = lane & 3, dcq = lane >> 2;
    float* batch = out + 12288;
    size_t hd0 = (size_t)((ls << 2) + b) << 4;

    // fully-tail block: pure zero-store, no GEMM
    if (Tbase >= total) {
        f32x4 z = {0.f, 0.f, 0.f, 0.f};
#pragma unroll
        for (int r = 0; r < 4; ++r) {
#pragma unroll
            for (int gi = 0; gi < 4; ++gi) {
                int flat = (wv << 2) + gi;
                int hq = flat >> 3, t4 = flat & 7;
                int tglob = Tbase + (t4 << 2) + toff;
                int h = (hq << 2) + r;
                if (tglob < Tmax) {
                    float* dst = batch + ((hd0 + h) * (size_t)Tmax + tglob) * 64;
                    *(f32x4*)(dst + (dcq << 2)) = z;
                }
            }
        }
        return;
    }

    // issue A(0) as early as possible (wave-private region)
    const char* gpanel = (const char*)Wp + (((size_t)(ls * 6)) << 16) + (wv << 13) + (lane << 4);
    char* lbase = ((char*)&As[0][0]) + (wv << 13);
#pragma unroll
    for (int it = 0; it < 8; ++it)
        __builtin_amdgcn_global_load_lds(
            (const __attribute__((address_space(1))) void*)(gpanel + it * 1024),
            (__attribute__((address_space(3))) void*)(lbase + it * 1024), 16, 0, 0);

    // bias -> biasT[h][beta*16+dmid]
    {
        int i0 = tid, i1 = tid + 512;
        biasT[i0 & 15][((i0 >> 8) << 4) + ((i0 & 255) >> 4)] = bias[(ls << 10) + i0];
        biasT[i1 & 15][((i1 >> 8) << 4) + ((i1 & 255) >> 4)] = bias[(ls << 10) + i1];
    }

    int beta = wv >> 1, oh = wv & 1;
    int p = lane & 15, q = lane >> 4;

    // per-lane B row decode (clamped -> addresses always valid)
    int c1 = ws[16 + (b << 2) + 1];
    int c2 = ws[16 + (b << 2) + 2];
    int c3 = ws[16 + (b << 2) + 3];
    const unsigned short* Brow[2];
    bool bval[2];
#pragma unroll
    for (int n = 0; n < 2; ++n) {
        int Ti = Tbase + (n << 4) + p;
        bval[n] = Ti < total;
        int TiC = bval[n] ? Ti : (total - 1);
        int sj = (TiC >= c1) + (TiC >= c2) + (TiC >= c3);
        int cum = sj == 0 ? 0 : (sj == 1 ? c1 : (sj == 2 ? c2 : c3));
        int row = ((b << 2) + sj) * 256 + (TiC - cum);
        Brow[n] = Lp + (size_t)row * 768 + beta * 192 + (q << 3);
    }

    f32x4 acc[8][2] = {};
    const bf16x8 bz = {};

    bf16x8 bc0 = ldfrag_masked(Brow[0], bval[0]);
    bf16x8 bc1 = ldfrag_masked(Brow[1], bval[1]);

#pragma unroll
    for (int cc = 0; cc < 6; ++cc) {
        bf16x8 bn0 = bz, bn1 = bz;
        if (cc < 5) {
            bn0 = ldfrag_masked(Brow[0] + ((cc + 1) << 5), bval[0]);
            bn1 = ldfrag_masked(Brow[1] + ((cc + 1) << 5), bval[1]);
            asm volatile("s_waitcnt vmcnt(2)" ::: "memory");   // A(cc)+B(cc) done; B(cc+1) in flight
        } else {
            asm volatile("s_waitcnt vmcnt(0)" ::: "memory");
        }
        __builtin_amdgcn_sched_barrier(0);
#pragma unroll
        for (int r8 = 0; r8 < 8; ++r8) {
            int row = (wv << 7) + (r8 << 4) + p;
            bf16x8 af = ldfrag(&As[row][(q ^ ((row >> 1) & 3)) << 3]);
            acc[r8][0] = __builtin_amdgcn_mfma_f32_16x16x32_bf16(af, bc0, acc[r8][0], 0, 0, 0);
            acc[r8][1] = __builtin_amdgcn_mfma_f32_16x16x32_bf16(af, bc1, acc[r8][1], 0, 0, 0);
        }
        if (cc < 5) {
            asm volatile("s_waitcnt lgkmcnt(0)" ::: "memory");  // frag reads done -> region reusable
            __builtin_amdgcn_sched_barrier(0);
            const char* g = gpanel + ((size_t)(cc + 1) << 16);
#pragma unroll
            for (int it = 0; it < 8; ++it)
                __builtin_amdgcn_global_load_lds(
                    (const __attribute__((address_space(1))) void*)(g + it * 1024),
                    (__attribute__((address_space(3))) void*)(lbase + it * 1024), 16, 0, 0);
        }
        bc0 = bn0; bc1 = bn1;
    }

    __syncthreads();   // all waves done with As before Ltr reuse; biasT visible

    // ---- epilogue: transpose via Ltr f32[128][68], 1KB-burst stores, tail zeros ----
    float* Ltr = (float*)&As[0][0];
    int col0 = (beta << 4) + (oh << 3);

#pragma unroll
    for (int r = 0; r < 4; ++r) {
#pragma unroll
        for (int n = 0; n < 2; ++n) {
            int rowL = (((n << 4) + p) << 2) + q;
            f32x4 v0 = { acc[0][n][r], acc[1][n][r], acc[2][n][r], acc[3][n][r] };
            f32x4 v1 = { acc[4][n][r], acc[5][n][r], acc[6][n][r], acc[7][n][r] };
            *(f32x4*)(Ltr + rowL * 68 + col0) = v0;
            *(f32x4*)(Ltr + rowL * 68 + col0 + 4) = v1;
        }
        __syncthreads();
#pragma unroll
        for (int gi = 0; gi < 4; ++gi) {
            int flat = (wv << 2) + gi;
            int hq = flat >> 3, t4 = flat & 7;
            int tloc = (t4 << 2) + toff;
            int h = (hq << 2) + r;
            int tglob = Tbase + tloc;
            if (tglob < Tmax) {
                f32x4 v;
                if (tglob < total) {
                    v = *(const f32x4*)(Ltr + ((tloc << 2) + hq) * 68 + (dcq << 2));
                    v += *(const f32x4*)&biasT[h][dcq << 2];
                } else {
                    v = (f32x4){0.f, 0.f, 0.f, 0.f};
                }
                float* dst = batch + ((hd0 + h) * (size_t)Tmax + tglob) * 64;
                *(f32x4*)(dst + (dcq << 2)) = v;
            }
        }
        __syncthreads();
    }
}

// ---------------- fallback path (ws too small) ----------------
__global__ void cums_kernel(const int* __restrict__ mask, int* __restrict__ ws,
                            float* __restrict__ valid_out, int Tmax) {
    int tid = threadIdx.x;
    int w = tid >> 6, lane = tid & 63;
    int m = mask[w * 256 + lane] + mask[w * 256 + lane + 64] +
            mask[w * 256 + lane + 128] + mask[w * 256 + lane + 192];
#pragma unroll
    for (int off = 32; off > 0; off >>= 1) m += __shfl_down(m, off);
    if (lane == 0) ws[w] = m;
    __syncthreads();
    if (tid == 0) {
        for (int b = 0; b < 4; ++b) {
            int c = 0;
            for (int j = 0; j < 4; ++j) { ws[16 + b * 4 + j] = c; c += ws[b * 4 + j]; }
            ws[32 + b] = c;
        }
    }
    __syncthreads();
    for (int i = tid; i < 4 * Tmax; i += 1024) {
        int b = i / Tmax;
        int T = i - b * Tmax;
        valid_out[i] = (T < ws[32 + b]) ? 1.0f : 0.0f;
    }
}

__global__ void pooled_kernel(const float* __restrict__ lh, const int* __restrict__ mask,
                              const int* __restrict__ ws, float* __restrict__ pooled) {
    int bs = blockIdx.x / 12;
    int ec = blockIdx.x - bs * 12;
    int tid = threadIdx.x;
    int tg = tid >> 6, lane = tid & 63;
    int e = ec * 64 + lane;
    float s = 0.f;
    for (int t = tg; t < 256; t += 4) {
        float mf = (float)mask[bs * 256 + t];
        s += lh[(size_t)(bs * 256 + t) * 768 + e] * mf;
    }
    __shared__ float red[4][64];
    red[tg][lane] = s;
    __syncthreads();
    if (tg == 0) {
        float tot = red[0][lane] + red[1][lane] + red[2][lane] + red[3][lane];
        pooled[bs * 768 + e] = tot / (float)ws[bs];
    }
}

__global__ void zerotail_kernel(float* __restrict__ batch, const int* __restrict__ ws,
                                int Tmax) {
    int rr = blockIdx.x;
    int b = rr >> 9;
    int rem = rr & 511;
    int l = rem >> 5, s = (rem >> 4) & 1, h = rem & 15;
    int total = ws[32 + b];
    int span = Tmax - total;
    if (span <= 0) return;
    float* row = batch + (((size_t)((l * 2 + s) * 4 + b) * 16 + h) * (size_t)Tmax + total) * 64;
    f32x4 z = {0.f, 0.f, 0.f, 0.f};
    int nchunk = span << 4;
    for (int j = threadIdx.x; j < nchunk; j += 256)
        *(f32x4*)(row + (j << 2)) = z;
}

__global__ __launch_bounds__(512, 4) void gemm_fb(
    const float* __restrict__ lh, const float* __restrict__ wgt,
    const float* __restrict__ bias, const int* __restrict__ ws,
    float* __restrict__ out, int Tmax) {
    __shared__ __align__(16) unsigned short As[1024][32];
    __shared__ __align__(16) float biasT[16][64];

    int x = blockIdx.x;
    int xcd = x & 7;
    int rest = x >> 3;
    int lsq = rest >> 7;
    int rb = rest & 127;
    int ls = (lsq << 3) + xcd;
    int bs = rb >> 3;
    int tq = rb & 7;

    int len = ws[bs];
    int tbase = tq << 5;
    if (tbase >= len) return;

    int tid = threadIdx.x;
    {
        int i0 = tid, i1 = tid + 512;
        biasT[i0 & 15][((i0 >> 8) << 4) + ((i0 & 255) >> 4)] = bias[(ls << 10) + i0];
        biasT[i1 & 15][((i1 >> 8) << 4) + ((i1 & 255) >> 4)] = bias[(ls << 10) + i1];
    }

    int lane = tid & 63;
    int wv = tid >> 6;
    int beta = wv >> 1, oh = wv & 1;
    int p = lane & 15, q = lane >> 4;

    f32x4 acc[8][2] = {};

#pragma unroll
    for (int cc = 0; cc < 6; ++cc) {
        const int kk = cc << 5;
        const float* Awg = wgt + (size_t)ls * 196608;
        int arow0 = tid >> 2;
        int achk = tid & 3;
#pragma unroll
        for (int it = 0; it < 8; ++it) {
            int row = arow0 + (it << 7);
            const float* src = Awg + row * 192 + kk + (achk << 3);
            f32x4 a0 = *(const f32x4*)src;
            f32x4 a1 = *(const f32x4*)(src + 4);
            u16x8 aw = { f2bf(a0[0]), f2bf(a0[1]), f2bf(a0[2]), f2bf(a0[3]),
                         f2bf(a1[0]), f2bf(a1[1]), f2bf(a1[2]), f2bf(a1[3]) };
            *(u16x8*)&As[row][(achk ^ ((row >> 1) & 3)) << 3] = aw;
        }
        bf16x8 bf[2];
        const float* Brow = lh + (size_t)bs * 196608 + (size_t)(tbase + p) * 768 +
                            beta * 192 + (q << 3) + kk;
#pragma unroll
        for (int n = 0; n < 2; ++n) {
            const float* bp = Brow + n * 16 * 768;
            f32x4 b0 = *(const f32x4*)bp;
            f32x4 b1 = *(const f32x4*)(bp + 4);
            u16x8 bw = { f2bf(b0[0]), f2bf(b0[1]), f2bf(b0[2]), f2bf(b0[3]),
                         f2bf(b1[0]), f2bf(b1[1]), f2bf(b1[2]), f2bf(b1[3]) };
            bf[n] = __builtin_bit_cast(bf16x8, bw);
        }
        __syncthreads();
#pragma unroll
        for (int r8 = 0; r8 < 8; ++r8) {
            int row = (beta << 8) + (oh << 7) + (r8 << 4) + p;
            bf16x8 af = ldfrag(&As[row][(q ^ ((row >> 1) & 3)) << 3]);
            acc[r8][0] = __builtin_amdgcn_mfma_f32_16x16x32_bf16(af, bf[0], acc[r8][0], 0, 0, 0);
            acc[r8][1] = __builtin_amdgcn_mfma_f32_16x16x32_bf16(af, bf[1], acc[r8][1], 0, 0, 0);
        }
        __syncthreads();
    }

    float* Ltr = (float*)&As[0][0];
    int cum = ws[16 + bs];
    int b = bs >> 2;
    float* batch = out + 12288;
    size_t hd0 = (size_t)((ls << 2) + b) << 4;

    int toff = lane & 3, dcq = lane >> 2;
    int col0 = (beta << 4) + (oh << 3);

#pragma unroll
    for (int r = 0; r < 4; ++r) {
#pragma unroll
        for (int n = 0; n < 2; ++n) {
            int rowL = (((n << 4) + p) << 2) + q;
            f32x4 v0 = { acc[0][n][r], acc[1][n][r], acc[2][n][r], acc[3][n][r] };
            f32x4 v1 = { acc[4][n][r], acc[5][n][r], acc[6][n][r], acc[7][n][r] };
            *(f32x4*)(Ltr + rowL * 68 + col0) = v0;
            *(f32x4*)(Ltr + rowL * 68 + col0 + 4) = v1;
        }
        __syncthreads();
#pragma unroll
        for (int gi = 0; gi < 4; ++gi) {
            int flat = (wv << 2) + gi;
            int hq = flat >> 3, t4 = flat & 7;
            int tloc = (t4 << 2) + toff;
            int h = (hq << 2) + r;
            int tglob = tbase + tloc;
            f32x4 v = *(const f32x4*)(Ltr + ((tloc << 2) + hq) * 68 + (dcq << 2));
            v += *(const f32x4*)&biasT[h][dcq << 2];
            if (tglob < len) {
                float* dst = batch + ((hd0 + h) * (size_t)Tmax + cum + tglob) * 64;
                *(f32x4*)(dst + (dcq << 2)) = v;
            }
        }
        __syncthreads();
    }
}

extern "C" void kernel_launch(void* const* d_in, const int* in_sizes, int n_in,
                              void* d_out, int out_size, void* d_ws, size_t ws_size,
                              hipStream_t stream) {
    const float* lh   = (const float*)d_in[0];
    const int*   mask = (const int*)d_in[1];
    const float* wgt  = (const float*)d_in[2];
    const float* bias = (const float*)d_in[3];
    float* out = (float*)d_out;
    int* ws = (int*)d_ws;

    int Tmax = (out_size - 12288) / 131076;
    int nT = (Tmax + 31) >> 5;

    unsigned short* Wp = (unsigned short*)((char*)d_ws + 1024);
    unsigned short* Lp = (unsigned short*)((char*)d_ws + 1024 + 12582912);
    const size_t need = 1024 + 12582912 + 6291456;
    bool packed = ws_size >= need;

    float* valid_out = out + 12288 + (size_t)131072 * Tmax;

    if (packed) {
        prep_kernel<<<4801, 256, 0, stream>>>(wgt, lh, mask, Wp, Lp, ws, out, valid_out, Tmax);
        gemm_t<<<128 * nT, 512, 0, stream>>>(Wp, Lp, bias, ws, out, Tmax, nT);
    } else {
        cums_kernel<<<1, 1024, 0, stream>>>(mask, ws, valid_out, Tmax);
        pooled_kernel<<<16 * 12, 256, 0, stream>>>(lh, mask, ws, out);
        zerotail_kernel<<<2048, 256, 0, stream>>>(out + 12288, ws, Tmax);
        gemm_fb<<<4096, 512, 0, stream>>>(lh, wgt, bias, ws, out, Tmax);
    }
}